// Round 1
// baseline (213.264 us; speedup 1.0000x reference)
//
#include <hip/hip_runtime.h>

// Problem constants (from reference): B=4, C=2, H=128, W=256
#define BB 4
#define CC 2
#define HH 128
#define WW 256
#define HO 512   // 4*H
#define WO4 256  // (4*W)/4  -- one float4 per j

// One block = one output row (b, y): 256 threads, thread j handles the 4
// sub-pixels d=0..3 at output x = 4*j+d. All threads in the block share
// (b, i=y/4), so the 6 cv rows needed (2 channels x {i-1,i,i+1}) are staged
// in LDS once per block (6 KB).
__global__ __launch_bounds__(256)
void spixel_upsample2d_kernel(const float* __restrict__ cv,
                              const float4* __restrict__ sp,
                              float4* __restrict__ out)
{
    const int j = threadIdx.x;        // 0..255  (coarse-pixel column)
    const int y = blockIdx.x & 511;   // output row within batch
    const int b = blockIdx.x >> 9;    // batch
    const int i = y >> 2;             // coarse-pixel row

    // Stage cv rows: srow[c][dy][jj] = cv[b, c, i+dy-1, jj] (0 if OOB row)
    __shared__ float srow[CC][3][WW];
    for (int r = threadIdx.x; r < CC * 3 * WW; r += 256) {
        const int c   = r / (3 * WW);
        const int rem = r - c * 3 * WW;
        const int dy  = rem / WW;
        const int jj  = rem - dy * WW;
        const int ii  = i + dy - 1;
        float v = 0.0f;
        if (ii >= 0 && ii < HH)
            v = cv[((b * CC + c) * HH + ii) * WW + jj];
        srow[c][dy][jj] = v;
    }
    __syncthreads();

    // sp channel (c*9+k) plane stride in float4 units
    const int plane = HO * WO4;                       // 131072
    const float4* spb = sp + (b * CC * 9) * plane + y * WO4 + j;

    float4 acc = make_float4(0.f, 0.f, 0.f, 0.f);

    #pragma unroll
    for (int c = 0; c < CC; ++c) {
        #pragma unroll
        for (int ky = 0; ky < 3; ++ky) {
            #pragma unroll
            for (int kx = 0; kx < 3; ++kx) {
                const int jj = j + kx - 1;
                const float p = (jj >= 0 && jj < WW) ? srow[c][ky][jj] : 0.0f;
                const int ch = c * 9 + ky * 3 + kx;
                const float4 s = spb[ch * plane];
                acc.x = fmaf(p, s.x, acc.x);
                acc.y = fmaf(p, s.y, acc.y);
                acc.z = fmaf(p, s.z, acc.z);
                acc.w = fmaf(p, s.w, acc.w);
            }
        }
    }

    out[(b * HO + y) * WO4 + j] = acc;
}

extern "C" void kernel_launch(void* const* d_in, const int* in_sizes, int n_in,
                              void* d_out, int out_size, void* d_ws, size_t ws_size,
                              hipStream_t stream) {
    const float*  cv = (const float*)d_in[0];                 // (4,2,1,128,256)
    const float4* sp = (const float4*)d_in[1];                // (4,18,512,1024)
    float4*       out = (float4*)d_out;                       // (4,1,512,1024)

    const dim3 grid(BB * HO);   // 2048 blocks: one per (b, y) output row
    const dim3 block(256);
    spixel_upsample2d_kernel<<<grid, block, 0, stream>>>(cv, sp, out);
}

// Round 3
// 203.371 us; speedup vs baseline: 1.0486x; 1.0486x over previous
//
#include <hip/hip_runtime.h>

// Problem constants: B=4, C=2, H=128, W=256 -> out (4,1,512,1024)
#define BB 4
#define CC 2
#define HH 128
#define WW 256
#define HO 512            // 4*H
#define WO4 256           // (4*W)/4 : one vec4 per coarse column j
#define PLANE (HO * WO4)  // vec4s per (b, ch) plane = 131072 (2 MB)

// Native clang vector type: __builtin_nontemporal_* accepts this (HIP's
// float4 is a class and is rejected).
typedef float vf4 __attribute__((ext_vector_type(4)));

// One block = one coarse row (b, i): 1024 threads = (a, j), a = sub-row 0..3,
// j = coarse column 0..255. Each thread produces output vec4 at
// (b, y=4i+a, x4=j). Per plane, the block reads 4 rows x 16 KiB = 64 KiB
// CONTIGUOUS (vs 4 KiB in R0) for better DRAM row locality. sp/out use
// non-temporal accesses so the streaming 151 MB doesn't evict cv from L2.
__global__ __launch_bounds__(1024)
void spixel_upsample2d_kernel(const float* __restrict__ cv,
                              const vf4* __restrict__ sp,
                              vf4* __restrict__ out)
{
    const int tid = threadIdx.x;
    const int j   = tid & 255;        // coarse column
    const int a   = tid >> 8;         // sub-row 0..3
    const int i   = blockIdx.x & 127; // coarse row
    const int b   = blockIdx.x >> 7;  // batch
    const int y   = (i << 2) | a;     // output row

    // Stage cv rows: srow[c][dy][jj] = cv[b, c, i+dy-1, jj] (0 if OOB row)
    __shared__ float srow[CC][3][WW];
    for (int r = tid; r < CC * 3 * WW; r += 1024) {
        const int c   = r / (3 * WW);
        const int rem = r - c * (3 * WW);
        const int dy  = rem / WW;
        const int jj  = rem - dy * WW;
        const int ii  = i + dy - 1;
        srow[c][dy][jj] = (ii >= 0 && ii < HH)
                            ? cv[((b * CC + c) * HH + ii) * WW + jj] : 0.0f;
    }
    __syncthreads();

    // Pull the 18 patch weights into registers (static indices only).
    float p[CC * 9];
    #pragma unroll
    for (int c = 0; c < CC; ++c)
        #pragma unroll
        for (int ky = 0; ky < 3; ++ky)
            #pragma unroll
            for (int kx = 0; kx < 3; ++kx) {
                const int jj = j + kx - 1;
                p[c * 9 + ky * 3 + kx] =
                    (jj >= 0 && jj < WW) ? srow[c][ky][jj] : 0.0f;
            }

    // 18 coalesced, non-temporal vec4 loads at static 2 MB plane offsets.
    const vf4* base = sp + (size_t)(b * CC * 9) * PLANE + y * WO4 + j;
    vf4 acc = (vf4){0.f, 0.f, 0.f, 0.f};
    #pragma unroll
    for (int ch = 0; ch < CC * 9; ++ch) {
        const vf4 s = __builtin_nontemporal_load(base + (size_t)ch * PLANE);
        acc.x = fmaf(p[ch], s.x, acc.x);
        acc.y = fmaf(p[ch], s.y, acc.y);
        acc.z = fmaf(p[ch], s.z, acc.z);
        acc.w = fmaf(p[ch], s.w, acc.w);
    }

    __builtin_nontemporal_store(acc, out + (size_t)(b * HO + y) * WO4 + j);
}

extern "C" void kernel_launch(void* const* d_in, const int* in_sizes, int n_in,
                              void* d_out, int out_size, void* d_ws, size_t ws_size,
                              hipStream_t stream) {
    const float* cv  = (const float*)d_in[0];   // (4,2,1,128,256)
    const vf4*   sp  = (const vf4*)d_in[1];     // (4,18,512,1024) as vec4
    vf4*         out = (vf4*)d_out;             // (4,1,512,1024)  as vec4

    const dim3 grid(BB * HH);   // 512 blocks: one per (b, coarse row i)
    const dim3 block(1024);
    spixel_upsample2d_kernel<<<grid, block, 0, stream>>>(cv, sp, out);
}